// Round 16
// baseline (23.122 us; speedup 1.0000x reference)
//
#include <hip/hip_runtime.h>

#define HID   64
#define NHD   8
#define IT    16          // i's per block -> 512 blocks = 2/CU
#define WAVES 8
#define JTW   32          // j's per wave (2 MFMA tiles of 16)
#define JT    (WAVES*JTW) // 256 j's per block

typedef _Float16 f16x8 __attribute__((ext_vector_type(8)));
typedef float    f32x4 __attribute__((ext_vector_type(4)));

// out[b,k,i,j] = sum_h relu( (u_j[h]+b1[h]) - u_i[h] ) * W2[h,k] + b2[k]
// r15 (21.2us, validated) with ONE change: the two dwordx4 stores are
// NONTEMPORAL. Theory: all r2-r15 kernels stream 67MB of dirty lines through
// the write-back L2; at 1x volume the kernel lifetime is short vs the L2
// eviction pipeline's ramp, so waves stall on dirty-line allocation (r8's 4x
// volume amortizes the ramp -> near-zero excess over byte floor). nt bypasses
// L2 and write-combines to HBM. r4's nt datum was confounded (serial MFMA
// chain); this isolates it.
__global__ __launch_bounds__(WAVES * 64, 4) void relposenc_x4nt(
    const float* __restrict__ xyz, const float* __restrict__ W1,
    const float* __restrict__ b1,  const float* __restrict__ W2,
    const float* __restrict__ b2,  float* __restrict__ out, int N) {

  __shared__ float    sW1b1[4][HID];
  __shared__ float    sW2p[HID][NHD + 1];
  __shared__ float    sB2[NHD];
  __shared__ _Float16 sU[IT][HID];

  const int tid  = threadIdx.x;
  const int wave = tid >> 6;
  const int lane = tid & 63;
  const int col  = lane & 15;
  const int hgrp = lane >> 4;
  const int b    = blockIdx.z;
  const int i0   = blockIdx.y * IT;
  const int j0   = blockIdx.x * JT + wave * JTW;

  const float* xb = xyz + (size_t)b * 3 * N;

  // ---- coalesced staging (validated r12) ----
  sW2p[tid >> 3][tid & 7] = W2[tid];
  if (tid < 4 * HID) {
    int r = tid >> 6, h = tid & 63;
    sW1b1[r][h] = (r < 3) ? W1[r * HID + h] : b1[h];
  }
  if (tid < NHD) sB2[tid] = b2[tid];
  for (int t = tid; t < IT * HID; t += WAVES * 64) {
    int ii = t >> 6, h = t & 63;
    int i  = i0 + ii;
    float u = fmaf(xb[i], W1[h],
              fmaf(xb[N + i], W1[HID + h],
                   xb[2 * N + i] * W1[2 * HID + h]));
    sU[ii][h] = (_Float16)u;
  }

  __syncthreads();

  // ---- B fragments: W2 natural layout; cols (heads) 8..15 zero ----
  f16x8 w2f[2];
  #pragma unroll
  for (int kb = 0; kb < 2; ++kb)
    #pragma unroll
    for (int e = 0; e < 8; ++e) {
      int h = kb * 32 + hgrp * 8 + e;
      w2f[kb][e] = (_Float16)((col < NHD) ? sW2p[h][col] : 0.f);
    }
  const float b2s = sB2[col & 7];

  // ---- aj = u_j + b1 (f16) for this lane's 2 j's ----
  f16x8 aj[2][2];
  #pragma unroll
  for (int t = 0; t < 2; ++t) {
    int j = j0 + t * 16 + col;
    float x0 = xb[j], x1 = xb[N + j], x2 = xb[2 * N + j];
    #pragma unroll
    for (int kb = 0; kb < 2; ++kb)
      #pragma unroll
      for (int e = 0; e < 8; ++e) {
        int h = kb * 32 + hgrp * 8 + e;
        float v = fmaf(x0, sW1b1[0][h],
                  fmaf(x1, sW1b1[1][h],
                  fmaf(x2, sW1b1[2][h], sW1b1[3][h])));
        aj[t][kb][e] = (_Float16)v;
      }
  }

  // store geometry: lane (col<8, hgrp) owns plane k=col, j = j0 + t*16 + hgrp*4
  const size_t baseOff =
      ((size_t)(b * NHD + (col & 7)) * N + i0) * N + j0 + hgrp * 4;

  const f16x8 z = {0, 0, 0, 0, 0, 0, 0, 0};

  for (int ii = 0; ii < IT; ++ii) {
    f16x8 u0 = *(const f16x8*)&sU[ii][hgrp * 8];
    f16x8 u1 = *(const f16x8*)&sU[ii][32 + hgrp * 8];

    f16x8 d00 = __builtin_elementwise_max(aj[0][0] - u0, z);
    f16x8 d01 = __builtin_elementwise_max(aj[0][1] - u1, z);
    f16x8 d10 = __builtin_elementwise_max(aj[1][0] - u0, z);
    f16x8 d11 = __builtin_elementwise_max(aj[1][1] - u1, z);

    f32x4 c0 = {b2s, b2s, b2s, b2s};
    f32x4 c1 = {b2s, b2s, b2s, b2s};
    c0 = __builtin_amdgcn_mfma_f32_16x16x32_f16(d00, w2f[0], c0, 0, 0, 0);
    c0 = __builtin_amdgcn_mfma_f32_16x16x32_f16(d01, w2f[1], c0, 0, 0, 0);
    c1 = __builtin_amdgcn_mfma_f32_16x16x32_f16(d10, w2f[0], c1, 0, 0, 0);
    c1 = __builtin_amdgcn_mfma_f32_16x16x32_f16(d11, w2f[1], c1, 0, 0, 0);

    if (col < NHD) {
      float* p = out + baseOff + (size_t)ii * N;
      __builtin_nontemporal_store(c0, (f32x4*)p);
      __builtin_nontemporal_store(c1, (f32x4*)(p + 16));
    }
  }
}

extern "C" void kernel_launch(void* const* d_in, const int* in_sizes, int n_in,
                              void* d_out, int out_size, void* d_ws, size_t ws_size,
                              hipStream_t stream) {
  const float* xyz = (const float*)d_in[0];
  const float* W1  = (const float*)d_in[1];
  const float* b1  = (const float*)d_in[2];
  const float* W2  = (const float*)d_in[3];
  const float* b2  = (const float*)d_in[4];
  float* out = (float*)d_out;

  const long long in0 = in_sizes[0];
  const int N = (int)((3LL * (long long)out_size) / (8LL * in0));
  const int B = (int)(in0 / (3LL * N));

  dim3 grid(N / JT, N / IT, B);
  relposenc_x4nt<<<grid, WAVES * 64, 0, stream>>>(xyz, W1, b1, W2, b2, out, N);
}

// Round 18
// 21.285 us; speedup vs baseline: 1.0863x; 1.0863x over previous
//
#include <hip/hip_runtime.h>

#define HID   64
#define NHD   8
#define IT    16          // i's per block -> 512 blocks = 2/CU
#define WAVES 8
#define JTW   32          // j's per wave (2 MFMA tiles of 16)
#define JT    (WAVES*JTW) // 256 j's per block

typedef _Float16 f16x8 __attribute__((ext_vector_type(8)));
typedef float    f32x4 __attribute__((ext_vector_type(4)));

// out[b,k,i,j] = sum_h relu( (u_j[h]+b1[h]) - u_i[h] ) * W2[h,k] + b2[k]
// r15 compute (validated, 21.2us) + wave-local LDS transpose drain (r17),
// FIXED: asm memory clobbers fence the deposit->read->next-deposit sequence
// so hipcc cannot hoist the ds_read above the ds_writes (cross-lane LDS flow
// is invisible to its single-thread alias analysis; HW same-wave DS ops are
// in-order, so compiler-level ordering is sufficient — no barrier needed).
// Result: ONE full-wave dwordx4 store per i per wave (8 planes x 128B runs,
// 64 active lanes) vs r15's two half-masked insts (8 x 64B).
__global__ __launch_bounds__(WAVES * 64, 4) void relposenc_wt2(
    const float* __restrict__ xyz, const float* __restrict__ W1,
    const float* __restrict__ b1,  const float* __restrict__ W2,
    const float* __restrict__ b2,  float* __restrict__ out, int N) {

  __shared__ float    sW1b1[4][HID];
  __shared__ float    sW2p[HID][NHD + 1];
  __shared__ float    sB2[NHD];
  __shared__ _Float16 sU[IT][HID];
  __shared__ float    sT[WAVES][256];   // 1KB per wave, wave-private

  const int tid  = threadIdx.x;
  const int wave = tid >> 6;
  const int lane = tid & 63;
  const int col  = lane & 15;
  const int hgrp = lane >> 4;
  const int b    = blockIdx.z;
  const int i0   = blockIdx.y * IT;
  const int j0   = blockIdx.x * JT + wave * JTW;

  const float* xb = xyz + (size_t)b * 3 * N;

  // ---- coalesced staging (validated r12) ----
  sW2p[tid >> 3][tid & 7] = W2[tid];
  if (tid < 4 * HID) {
    int r = tid >> 6, h = tid & 63;
    sW1b1[r][h] = (r < 3) ? W1[r * HID + h] : b1[h];
  }
  if (tid < NHD) sB2[tid] = b2[tid];
  for (int t = tid; t < IT * HID; t += WAVES * 64) {
    int ii = t >> 6, h = t & 63;
    int i  = i0 + ii;
    float u = fmaf(xb[i], W1[h],
              fmaf(xb[N + i], W1[HID + h],
                   xb[2 * N + i] * W1[2 * HID + h]));
    sU[ii][h] = (_Float16)u;
  }

  __syncthreads();

  // ---- B fragments: W2 natural layout; cols (heads) 8..15 zero ----
  f16x8 w2f[2];
  #pragma unroll
  for (int kb = 0; kb < 2; ++kb)
    #pragma unroll
    for (int e = 0; e < 8; ++e) {
      int h = kb * 32 + hgrp * 8 + e;
      w2f[kb][e] = (_Float16)((col < NHD) ? sW2p[h][col] : 0.f);
    }
  const float b2s = sB2[col & 7];

  // ---- aj = u_j + b1 (f16) for this lane's 2 j's ----
  f16x8 aj[2][2];
  #pragma unroll
  for (int t = 0; t < 2; ++t) {
    int j = j0 + t * 16 + col;
    float x0 = xb[j], x1 = xb[N + j], x2 = xb[2 * N + j];
    #pragma unroll
    for (int kb = 0; kb < 2; ++kb)
      #pragma unroll
      for (int e = 0; e < 8; ++e) {
        int h = kb * 32 + hgrp * 8 + e;
        float v = fmaf(x0, sW1b1[0][h],
                  fmaf(x1, sW1b1[1][h],
                  fmaf(x2, sW1b1[2][h], sW1b1[3][h])));
        aj[t][kb][e] = (_Float16)v;
      }
  }

  // LDS transpose offsets (floats, within this wave's 256-float region).
  // layout: plane p at p*32, j-quad q at ((q+p)&7)*4  (XOR-free swizzle)
  const int dep0 = col * 32 + (((hgrp)     + col) & 7) * 4;  // c0: quad hgrp
  const int dep1 = col * 32 + (((hgrp + 4) + col) & 7) * 4;  // c1: quad hgrp+4
  const int pP   = lane >> 3;         // plane this lane stores
  const int qQ   = lane & 7;          // j-quad this lane stores
  const int roff = pP * 32 + ((qQ + pP) & 7) * 4;

  // store: out[b, k=pP, i, j0 + qQ*4 .. +3]
  float* stBase = out + ((size_t)(b * NHD + pP) * N + i0) * N + j0 + qQ * 4;

  const f16x8 z = {0, 0, 0, 0, 0, 0, 0, 0};

  for (int ig = 0; ig < IT; ig += 4) {
    f32x4 sv[4];

    #pragma unroll
    for (int q = 0; q < 4; ++q) {
      const int ii = ig + q;
      f16x8 u0 = *(const f16x8*)&sU[ii][hgrp * 8];
      f16x8 u1 = *(const f16x8*)&sU[ii][32 + hgrp * 8];

      f16x8 d00 = __builtin_elementwise_max(aj[0][0] - u0, z);
      f16x8 d01 = __builtin_elementwise_max(aj[0][1] - u1, z);
      f16x8 d10 = __builtin_elementwise_max(aj[1][0] - u0, z);
      f16x8 d11 = __builtin_elementwise_max(aj[1][1] - u1, z);

      f32x4 c0 = {b2s, b2s, b2s, b2s};
      f32x4 c1 = {b2s, b2s, b2s, b2s};
      c0 = __builtin_amdgcn_mfma_f32_16x16x32_f16(d00, w2f[0], c0, 0, 0, 0);
      c0 = __builtin_amdgcn_mfma_f32_16x16x32_f16(d01, w2f[1], c0, 0, 0, 0);
      c1 = __builtin_amdgcn_mfma_f32_16x16x32_f16(d10, w2f[0], c1, 0, 0, 0);
      c1 = __builtin_amdgcn_mfma_f32_16x16x32_f16(d11, w2f[1], c1, 0, 0, 0);

      // wave-local transpose round-trip. HW: same-wave DS ops are in-order.
      // The asm memory clobbers stop hipcc reordering the read vs the writes
      // (cross-lane LDS flow is invisible to single-thread alias analysis).
      if (col < NHD) {
        *(f32x4*)&sT[wave][dep0] = c0;
        *(f32x4*)&sT[wave][dep1] = c1;
      }
      asm volatile("" ::: "memory");   // writes before read
      sv[q] = *(const f32x4*)&sT[wave][roff];
      asm volatile("" ::: "memory");   // read before next iter's writes
    }

    // 4-deep burst of full-wave 1KB dwordx4 stores
    #pragma unroll
    for (int q = 0; q < 4; ++q)
      *(f32x4*)(stBase + (size_t)(ig + q) * N) = sv[q];
  }
}

extern "C" void kernel_launch(void* const* d_in, const int* in_sizes, int n_in,
                              void* d_out, int out_size, void* d_ws, size_t ws_size,
                              hipStream_t stream) {
  const float* xyz = (const float*)d_in[0];
  const float* W1  = (const float*)d_in[1];
  const float* b1  = (const float*)d_in[2];
  const float* W2  = (const float*)d_in[3];
  const float* b2  = (const float*)d_in[4];
  float* out = (float*)d_out;

  const long long in0 = in_sizes[0];
  const int N = (int)((3LL * (long long)out_size) / (8LL * in0));
  const int B = (int)(in0 / (3LL * N));

  dim3 grid(N / JT, N / IT, B);
  relposenc_wt2<<<grid, WAVES * 64, 0, stream>>>(xyz, W1, b1, W2, b2, out, N);
}